// Round 5
// baseline (370.111 us; speedup 1.0000x reference)
//
#include <hip/hip_runtime.h>

// SRLSecondOrderScorer: B=2, N=128, D_IN=1024, D=150. Inputs f32, outputs f32.
// Round 10: r9 + Y-staging fix (p*8 stride, full row coverage — the p*16 gap
// left stale bytes -> NaN in r8). tmp-in-registers via swapped phase-1 + shfl
// repack; 43KB LDS union -> 3 blocks/CU; half-plane sym. 6 launches total.
// Chain per group g: TT3g[g][(j*160+i)][k] = bf16(T_g[i][k][j])
//   wz3g[g][bz][j*160+i] = sum_k Z[bz,k]*TT3                     (MFMA GEMM)
//   tmp[x][j]            = sum_i X[b,x,i]*wz3     (in-register, fused)
//   s[g][bz][x][y]       = sum_j tmp*Y[b,y,j]     (+ triu_sym for g=1..3,
//                                                  upper-tri only for g=4,5)
// H rows padded to 160 with exact zeros => all K-padding inert.

#define DD    150
#define KP    160
#define OUTBLK 4194304       // 2*128^3 floats
#define NWZ   24064          // wz3 row stride (188*128); cols>=24000 written zero
#define TTG   3840000        // shorts per TT3 group (24000 rows x 160)
#define WZG   (256*NWZ)      // shorts per wz3 group
#define HROW  (256*160)      // shorts per H region

__device__ __forceinline__ unsigned short f2u(float f) {  // RNE f32->bf16
  unsigned x = __float_as_uint(f);
  x += 0x7FFFu + ((x >> 16) & 1u);
  return (unsigned short)(x >> 16);
}

typedef __attribute__((ext_vector_type(8))) short frag8;
typedef __attribute__((ext_vector_type(4))) float facc4;
typedef __attribute__((ext_vector_type(4))) unsigned uint4v;

__constant__ int c_zsel[6] = {2, 2, 2, 2, 0, 1};  // Z region per group (sh,st,pp = 0,1,2)
__constant__ int c_xsel[6] = {0, 0, 0, 1, 2, 2};
__constant__ int c_ysel[6] = {1, 1, 0, 1, 2, 2};

// ---------------- MLP split-K partials: P[m][ks][bn][160] ----------------
__global__ __launch_bounds__(256) void mlp_partial(
    const float* __restrict__ x,
    const float* __restrict__ W0, const float* __restrict__ W1, const float* __restrict__ W2,
    float* __restrict__ P)
{
  int m = blockIdx.x, bt = blockIdx.y, ks = blockIdx.z;
  const float* W = (m == 0) ? W0 : (m == 1) ? W1 : W2;
  int bn0 = bt * 32, k0 = ks * 128;
  __shared__ float xs[32][132];
  int tid = threadIdx.x;
  for (int e = 0; e < 4; ++e) {
    int l = e * 256 + tid;
    int row = l >> 5, c4 = l & 31;
    float4 v = *(const float4*)&x[(bn0 + row) * 1024 + k0 + c4 * 4];
    xs[row][c4 * 4 + 0] = v.x; xs[row][c4 * 4 + 1] = v.y;
    xs[row][c4 * 4 + 2] = v.z; xs[row][c4 * 4 + 3] = v.w;
  }
  __syncthreads();
  int tj = tid & 15, tt = tid >> 4, r = tt * 2;
  int dd[10];
  #pragma unroll
  for (int u = 0; u < 10; ++u) { int d = tj + 16 * u; dd[u] = d < 150 ? d : 149; }
  float a0[10], a1[10];
  #pragma unroll
  for (int u = 0; u < 10; ++u) { a0[u] = 0.f; a1[u] = 0.f; }
  for (int k = 0; k < 128; ++k) {
    float xa = xs[r][k], xb = xs[r + 1][k];
    const float* wr = W + (long long)(k0 + k) * 150;
    #pragma unroll
    for (int u = 0; u < 10; ++u) {
      float w = wr[dd[u]];
      a0[u] += xa * w; a1[u] += xb * w;
    }
  }
  float* Pb = P + (long long)(m * 8 + ks) * 256 * 160;
  #pragma unroll
  for (int u = 0; u < 10; ++u) {
    int d = tj + 16 * u;
    Pb[(bn0 + r) * 160 + d]     = a0[u];
    Pb[(bn0 + r + 1) * 160 + d] = a1[u];
  }
}

// ---------------- MLP reduce: H[m][bn][160] bf16 (pads exact zero) ----------------
__global__ __launch_bounds__(256) void mlp_reduce(
    const float* __restrict__ P,
    const float* __restrict__ B0, const float* __restrict__ B1, const float* __restrict__ B2,
    unsigned short* __restrict__ H)
{
  int o = blockIdx.x * 256 + threadIdx.x;     // < 3*256*160
  int d = o % 160;
  int bn = (o / 160) & 255;
  int m = o / (160 * 256);
  float v = 0.f;
  if (d < 150) {
    const float* Bv = (m == 0) ? B0 : (m == 1) ? B1 : B2;
    v = Bv[d];
    #pragma unroll
    for (int ks = 0; ks < 8; ++ks)
      v += P[((long long)(m * 8 + ks) * 256 + bn) * 160 + d];
    v = v > 0.f ? v : 0.1f * v;
  }
  H[o] = f2u(v);
}

// ------ TT3g[g][(j*160+i)][k] = bf16(T_g[i][k][j]); i,k pads zero; all 6 groups ------
struct TPtrs { const float* t[6]; };
__global__ __launch_bounds__(256) void tt_kernel(TPtrs tp, unsigned short* __restrict__ TT3)
{
  int i = blockIdx.x;                  // 0..159
  int ky = blockIdx.y % 5, jy = blockIdx.y / 5;
  int k0 = ky * 32, j0 = jy * 32;
  int g = blockIdx.z;
  const float* T = tp.t[g];
  unsigned short* TT = TT3 + (long long)g * TTG;
  __shared__ float tl[32][33];
  int tid = threadIdx.x;
  #pragma unroll
  for (int e = 0; e < 4; ++e) {
    int l = e * 256 + tid;
    int r = l >> 5, c = l & 31;
    float v = 0.f;
    if (i < 150 && k0 + r < 150 && j0 + c < 150)
      v = T[i * 22500 + (k0 + r) * 150 + (j0 + c)];
    tl[r][c] = v;
  }
  __syncthreads();
  #pragma unroll
  for (int e = 0; e < 4; ++e) {
    int l = e * 256 + tid;
    int rr = l >> 5, cc = l & 31;
    if (j0 + rr < 150)
      TT[(long long)((j0 + rr) * 160 + i) * 160 + k0 + cc] = f2u(tl[cc][rr]);
  }
}

// ---- wz3g[g][m][n] = sum_k Z_g[m,k]*TT3g[g][n][k]; grid (188, 2, 6), bf16 out ----
__global__ __launch_bounds__(256) void wz_gemm(
    const unsigned short* __restrict__ Hb, const unsigned short* __restrict__ TT3,
    unsigned short* __restrict__ wz3)
{
  constexpr int LR = 72;
  __shared__ unsigned short lA[128 * LR];
  __shared__ unsigned short lB[128 * LR];
  int g = blockIdx.z, tid = threadIdx.x;
  const unsigned short* Ab = Hb + c_zsel[g] * HROW + blockIdx.y * 128 * 160;
  const unsigned short* Bb = TT3 + (long long)g * TTG;
  int n0 = blockIdx.x * 128;
  int wave = tid >> 6, lane = tid & 63;
  int l15 = lane & 15, lq = lane >> 4;
  int mw = (wave & 1) * 64, nw = (wave >> 1) * 64;
  facc4 acc[4][4];
  #pragma unroll
  for (int i = 0; i < 4; ++i)
    #pragma unroll
    for (int j = 0; j < 4; ++j) acc[i][j] = (facc4){0.f, 0.f, 0.f, 0.f};
  for (int ch = 0; ch < 3; ++ch) {
    int k0 = ch << 6;
    int sh = (ch == 2) ? 2 : 3, upr = 1 << sh;
    for (int u = tid; u < 128 * upr; u += 256) {
      int row = u >> sh, off = (u & (upr - 1)) << 3;
      *(uint4*)&lA[row * LR + off] = *(const uint4*)&Ab[row * 160 + k0 + off];
    }
    for (int u = tid; u < 128 * upr; u += 256) {
      int row = u >> sh, off = (u & (upr - 1)) << 3;
      int gn = n0 + row;
      uint4 v; v.x = 0u; v.y = 0u; v.z = 0u; v.w = 0u;
      if (gn < 24000) v = *(const uint4*)&Bb[(long long)gn * 160 + k0 + off];
      *(uint4*)&lB[row * LR + off] = v;
    }
    __syncthreads();
    int nks = (ch == 2) ? 1 : 2;
    for (int ks = 0; ks < nks; ++ks) {
      int ko = (ks << 5) + (lq << 3);
      frag8 af[4], bfr[4];
      #pragma unroll
      for (int i = 0; i < 4; ++i) af[i] = *(const frag8*)&lA[(mw + i * 16 + l15) * LR + ko];
      #pragma unroll
      for (int j = 0; j < 4; ++j) bfr[j] = *(const frag8*)&lB[(nw + j * 16 + l15) * LR + ko];
      #pragma unroll
      for (int i = 0; i < 4; ++i)
        #pragma unroll
        for (int j = 0; j < 4; ++j)
          acc[i][j] = __builtin_amdgcn_mfma_f32_16x16x32_bf16(af[i], bfr[j], acc[i][j], 0, 0, 0);
    }
    __syncthreads();
  }
  unsigned short* C = wz3 + (long long)g * WZG;
  int mb = blockIdx.y * 128 + mw;
  #pragma unroll
  for (int i = 0; i < 4; ++i)
    #pragma unroll
    for (int r = 0; r < 4; ++r) {
      int m = mb + i * 16 + lq * 4 + r;
      #pragma unroll
      for (int j = 0; j < 4; ++j)
        C[(long long)m * NWZ + n0 + nw + j * 16 + l15] = f2u(acc[i][j][r]);
    }
}

// ---- fused tmp+s per z (tmp kept in REGISTERS via swapped phase-1 + shfl
//      repack); sym via 33KB half-plane LDS buffer. grid (1536) ----
struct SPtrs { float* p[6]; };
__global__ __launch_bounds__(256, 3) void tmps_gemm(
    const unsigned short* __restrict__ Hb, const unsigned short* __restrict__ wz3,
    SPtrs sp)
{
  // LDS union (43008 B max -> 3 blocks/CU):
  //  p1: phase-1 staging (X 128x72, wz 160x72)
  //  Y : full Y tile [128][168] bf16 for phase 2 (stride 168 -> balanced banks)
  //  sq: half-plane f32 sym buffer [64][129] (pad -> mirror reads 2-way free)
  __shared__ union {
    struct { unsigned short X[128 * 72]; unsigned short W[160 * 72]; } p1;
    unsigned short Y[128 * 168];
    float sq[64 * 129];
  } sm;

  int z = blockIdx.x, tid = threadIdx.x;
  int g = z >> 8, bz = z & 255, b = bz >> 7;
  const unsigned short* Ab = Hb + c_xsel[g] * HROW + b * 128 * 160;  // X rows
  const unsigned short* Wb = wz3 + (long long)g * WZG + (long long)bz * NWZ;  // wz rows j
  int wave = tid >> 6, lane = tid & 63;
  int l15 = lane & 15, lq = lane >> 4;
  int X0 = wave * 32;                 // x-band per wave

  // ---------- phase 1 (swapped): accT[j-tile][x-tile] : D[j][x] = wz . X^T ----------
  facc4 accT[10][2];
  #pragma unroll
  for (int jt = 0; jt < 10; ++jt)
    #pragma unroll
    for (int xt = 0; xt < 2; ++xt) accT[jt][xt] = (facc4){0.f, 0.f, 0.f, 0.f};
  for (int ch = 0; ch < 3; ++ch) {
    int k0 = ch << 6;
    int sh = (ch == 2) ? 2 : 3, upr = 1 << sh;
    for (int u = tid; u < 128 * upr; u += 256) {
      int row = u >> sh, off = (u & (upr - 1)) << 3;
      *(uint4*)&sm.p1.X[row * 72 + off] = *(const uint4*)&Ab[row * 160 + k0 + off];
    }
    for (int u = tid; u < 160 * upr; u += 256) {
      int row = u >> sh, off = (u & (upr - 1)) << 3;
      uint4 v; v.x = 0u; v.y = 0u; v.z = 0u; v.w = 0u;
      if (row < 150) v = *(const uint4*)&Wb[row * 160 + k0 + off];
      *(uint4*)&sm.p1.W[row * 72 + off] = v;
    }
    __syncthreads();
    int nks = (ch == 2) ? 1 : 2;
    for (int ks = 0; ks < nks; ++ks) {
      int ko = (ks << 5) + (lq << 3);
      frag8 bx0 = *(const frag8*)&sm.p1.X[(X0 + l15) * 72 + ko];
      frag8 bx1 = *(const frag8*)&sm.p1.X[(X0 + 16 + l15) * 72 + ko];
      #pragma unroll
      for (int jt = 0; jt < 10; ++jt) {
        frag8 aw = *(const frag8*)&sm.p1.W[(jt * 16 + l15) * 72 + ko];
        accT[jt][0] = __builtin_amdgcn_mfma_f32_16x16x32_bf16(aw, bx0, accT[jt][0], 0, 0, 0);
        accT[jt][1] = __builtin_amdgcn_mfma_f32_16x16x32_bf16(aw, bx1, accT[jt][1], 0, 0, 0);
      }
    }
    __syncthreads();
  }

  // ---------- repack accT -> phase-2 A-frags (f2u + __shfl, no asm) ----------
  // accT[jt][xt] lane(lq',l15'): holds tmp[x = X0+16xt+l15'][j = 16jt+4lq'+r].
  // pA[xt][kb] lane(lq,l15) needs tmp[x = X0+16xt+l15][j = 32kb+8lq+e], e=0..7,
  // packed as words (e0,e1)(e2,e3)(e4,e5)(e6,e7).
  // word w source: register pk(r0,r1 | r2,r3) of jt-tile 2kb+(lq>=2), from
  // source lane 32*(lq&1) + 16*(w>=2) + l15.
  frag8 pA[2][5];
  {
    int s0 = ((lq & 1) << 5) + l15;
    int s2 = s0 + 16;
    bool lo = lq < 2;
    #pragma unroll
    for (int kb = 0; kb < 5; ++kb)
      #pragma unroll
      for (int xt = 0; xt < 2; ++xt) {
        unsigned w0l = (unsigned)f2u(accT[2 * kb][xt][0]) |
                       ((unsigned)f2u(accT[2 * kb][xt][1]) << 16);
        unsigned w1l = (unsigned)f2u(accT[2 * kb][xt][2]) |
                       ((unsigned)f2u(accT[2 * kb][xt][3]) << 16);
        unsigned w0h = (unsigned)f2u(accT[2 * kb + 1][xt][0]) |
                       ((unsigned)f2u(accT[2 * kb + 1][xt][1]) << 16);
        unsigned w1h = (unsigned)f2u(accT[2 * kb + 1][xt][2]) |
                       ((unsigned)f2u(accT[2 * kb + 1][xt][3]) << 16);
        unsigned a0 = __shfl(w0l, s0), b0 = __shfl(w0h, s0);
        unsigned a1 = __shfl(w1l, s0), b1 = __shfl(w1h, s0);
        unsigned a2 = __shfl(w0l, s2), b2 = __shfl(w0h, s2);
        unsigned a3 = __shfl(w1l, s2), b3 = __shfl(w1h, s2);
        uint4v uv;
        uv.x = lo ? a0 : b0;
        uv.y = lo ? a1 : b1;
        uv.z = lo ? a2 : b2;
        uv.w = lo ? a3 : b3;
        pA[xt][kb] = __builtin_bit_cast(frag8, uv);
      }
  }

  // ---------- stage full Y [128][168] (2 threads/row, 10 contiguous uint4 each) ----------
  const unsigned short* Yb = Hb + c_ysel[g] * HROW + b * 128 * 160;
  {
    int y = tid & 127, part = tid >> 7;
    #pragma unroll
    for (int p = 0; p < 10; ++p) {
      int off = part * 80 + p * 8;
      *(uint4*)&sm.Y[y * 168 + off] = *(const uint4*)&Yb[y * 160 + off];
    }
  }
  __syncthreads();

  // ---------- phase 2: s[x][y] = sum_j tmp[x][j] * Y[y][j] ----------
  facc4 acc2[2][8];
  #pragma unroll
  for (int xt = 0; xt < 2; ++xt)
    #pragma unroll
    for (int yt = 0; yt < 8; ++yt) acc2[xt][yt] = (facc4){0.f, 0.f, 0.f, 0.f};
  #pragma unroll
  for (int ks = 0; ks < 5; ++ks) {
    int ko = (ks << 5) + (lq << 3);
    #pragma unroll
    for (int yt = 0; yt < 8; ++yt) {
      frag8 by = *(const frag8*)&sm.Y[(yt * 16 + l15) * 168 + ko];
      acc2[0][yt] = __builtin_amdgcn_mfma_f32_16x16x32_bf16(pA[0][ks], by, acc2[0][yt], 0, 0, 0);
      acc2[1][yt] = __builtin_amdgcn_mfma_f32_16x16x32_bf16(pA[1][ks], by, acc2[1][yt], 0, 0, 0);
    }
  }

  // ---------- epilogue ----------
  // acc2 lane(q,c): x = X0 + xt*16 + 4q + r, y = yt*16 + c.
  float* C = sp.p[g] + (long long)bz * 16384;
  if (g == 0) {
    #pragma unroll
    for (int xt = 0; xt < 2; ++xt)
      #pragma unroll
      for (int r = 0; r < 4; ++r) {
        int x = X0 + xt * 16 + lq * 4 + r;
        #pragma unroll
        for (int yt = 0; yt < 8; ++yt)
          C[x * 128 + yt * 16 + l15] = acc2[xt][yt][r];
      }
  } else if (g >= 4) {
    // cop groups: cop_kernel only reads sx<=sy -> upper triangle only
    #pragma unroll
    for (int xt = 0; xt < 2; ++xt)
      #pragma unroll
      for (int r = 0; r < 4; ++r) {
        int x = X0 + xt * 16 + lq * 4 + r;
        #pragma unroll
        for (int yt = 0; yt < 8; ++yt) {
          int y = yt * 16 + l15;
          if (x <= y) C[x * 128 + y] = acc2[xt][yt][r];
        }
      }
  } else {
    // fused triu_sym: direct upper (y>=x) from regs, mirror via half-plane LDS.
    #pragma unroll
    for (int xt = 0; xt < 2; ++xt)
      #pragma unroll
      for (int r = 0; r < 4; ++r) {
        int x = X0 + xt * 16 + lq * 4 + r;
        #pragma unroll
        for (int yt = 0; yt < 8; ++yt) {
          int y = yt * 16 + l15;
          if (y >= x) C[x * 128 + y] = acc2[xt][yt][r];
        }
      }
    __syncthreads();   // all Y frag reads done before sq overwrites the union
    // Round A: waves 0,1 stage rows x in [0,64)
    if (wave < 2) {
      #pragma unroll
      for (int xt = 0; xt < 2; ++xt)
        #pragma unroll
        for (int r = 0; r < 4; ++r) {
          int x = X0 + xt * 16 + lq * 4 + r;
          #pragma unroll
          for (int yt = 0; yt < 8; ++yt)
            sm.sq[x * 129 + yt * 16 + l15] = acc2[xt][yt][r];
        }
    }
    __syncthreads();
    // mirror A: out[x][y] = s[y][x] for y < min(x,64); wave handles its 32 rows
    for (int it = 0; it < 32; ++it) {
      int x = X0 + it;
      int y = lane;
      if (y < 64 && y < x) C[x * 128 + y] = sm.sq[y * 129 + x];
    }
    __syncthreads();
    // Round B: waves 2,3 stage rows x in [64,128)
    if (wave >= 2) {
      #pragma unroll
      for (int xt = 0; xt < 2; ++xt)
        #pragma unroll
        for (int r = 0; r < 4; ++r) {
          int x = X0 + xt * 16 + lq * 4 + r;
          #pragma unroll
          for (int yt = 0; yt < 8; ++yt)
            sm.sq[(x - 64) * 129 + yt * 16 + l15] = acc2[xt][yt][r];
        }
    }
    __syncthreads();
    // mirror B: out[x][y] = s[y][x] for 64 <= y < x; 64 rows split 16/wave
    for (int it = 0; it < 16; ++it) {
      int x = 64 + wave * 16 + it;
      int y = 64 + lane;
      if (y < x) C[x * 128 + y] = sm.sq[(y - 64) * 129 + x];
    }
  }
}

// ---------- cop: out[b,x,y,z] = ss[g][b,z,min(x,y),max(x,y)]; grid (512,4,4) ----------
__global__ __launch_bounds__(256) void cop_kernel(
    const float* __restrict__ ss, float* __restrict__ out)
{
  int w0 = blockIdx.x << 5;
  int z0 = blockIdx.y << 5;
  int g  = blockIdx.z >> 1, b = blockIdx.z & 1;
  const float* sg = ss + (long long)g * OUTBLK;
  float* outp = out + (long long)(4 + g) * OUTBLK;
  __shared__ float tl[32][33];
  int tid = threadIdx.x;
  #pragma unroll
  for (int e = 0; e < 4; ++e) {
    int l = e * 256 + tid;
    int r = l >> 5, c = l & 31;
    int w = w0 + c;
    int xx = w >> 7, yy = w & 127;
    int sx = xx < yy ? xx : yy;
    int sy = xx < yy ? yy : xx;
    tl[r][c] = sg[(((b << 7) + z0 + r) << 14) + (sx << 7) + sy];
  }
  __syncthreads();
  #pragma unroll
  for (int e = 0; e < 4; ++e) {
    int l = e * 256 + tid;
    int rr = l >> 5, cc = l & 31;
    outp[(b << 21) + ((w0 + rr) << 7) + z0 + cc] = tl[cc][rr];
  }
}

extern "C" void kernel_launch(void* const* d_in, const int* in_sizes, int n_in,
                              void* d_out, int out_size, void* d_ws, size_t ws_size,
                              hipStream_t stream)
{
  const float* x   = (const float*)d_in[0];
  const float* Wsh = (const float*)d_in[1];
  const float* bsh = (const float*)d_in[2];
  const float* Wst = (const float*)d_in[3];
  const float* bst = (const float*)d_in[4];
  const float* Wp  = (const float*)d_in[5];
  const float* bp  = (const float*)d_in[6];
  TPtrs tp;
  tp.t[0] = (const float*)d_in[8];   // T_ph    (span_psh)
  tp.t[1] = (const float*)d_in[7];   // T_pt    (span_pst)
  tp.t[2] = (const float*)d_in[9];   // T_phsib
  tp.t[3] = (const float*)d_in[10];  // T_ptsib
  tp.t[4] = (const float*)d_in[11];  // T_phcop
  tp.t[5] = (const float*)d_in[12];  // T_ptcop
  float* out = (float*)d_out;
  char* wsb = (char*)d_ws;

  // ws layout (bytes): H 245,760 | TT3g 46,080,000 | wz3g 73,924,608
  // P (7.9MB) aliases wz3g (dead before wz writes); ss (33.6MB) aliases TT3g
  // (TT3 fully consumed by wz_gemm before tmps_gemm writes ss).
  unsigned short* Hb   = (unsigned short*)(wsb);
  unsigned short* TT3  = (unsigned short*)(wsb + 245760);
  unsigned short* wz3  = (unsigned short*)(wsb + 46325760);
  float* P  = (float*)wz3;
  float* ss = (float*)TT3;

  SPtrs sp;
  sp.p[0] = out + 0LL * OUTBLK;
  sp.p[1] = out + 1LL * OUTBLK;
  sp.p[2] = out + 2LL * OUTBLK;
  sp.p[3] = out + 3LL * OUTBLK;
  sp.p[4] = ss;
  sp.p[5] = ss + OUTBLK;

  mlp_partial<<<dim3(3, 8, 8),    256, 0, stream>>>(x, Wsh, Wst, Wp, P);
  mlp_reduce <<<dim3(480),        256, 0, stream>>>(P, bsh, bst, bp, Hb);
  tt_kernel  <<<dim3(160, 25, 6), 256, 0, stream>>>(tp, TT3);
  wz_gemm    <<<dim3(188, 2, 6),  256, 0, stream>>>(Hb, TT3, wz3);
  tmps_gemm  <<<dim3(1536),       256, 0, stream>>>(Hb, wz3, sp);
  cop_kernel <<<dim3(512, 4, 4),  256, 0, stream>>>(ss, out);
}

// Round 6
// 365.305 us; speedup vs baseline: 1.0132x; 1.0132x over previous
//
#include <hip/hip_runtime.h>

// SRLSecondOrderScorer: B=2, N=128, D_IN=1024, D=150. Inputs f32, outputs f32.
// Round 11: tmps_gemm reads X/Y direct from global (L2-hot H; no LDS staging),
// LDS = W only (23KB), phase-2 split in yt-halves (acc2 32 regs) -> 4 blocks/CU.
// Epilogue writes upper-triangle only for g1..5; new sym_fill kernel mirrors
// out blocks 1-3. 7 launches total.
// Chain per group g: TT3g[g][(j*160+i)][k] = bf16(T_g[i][k][j])
//   wz3g[g][bz][j*160+i] = sum_k Z[bz,k]*TT3                     (MFMA GEMM)
//   tmp[x][j]            = sum_i X[b,x,i]*wz3     (in-register, fused)
//   s[g][bz][x][y]       = sum_j tmp*Y[b,y,j]     (upper-tri for g>=1;
//                                                  sym_fill mirrors g=1..3)
// H rows padded to 160 with exact zeros => all K-padding inert.

#define DD    150
#define KP    160
#define OUTBLK 4194304       // 2*128^3 floats
#define NWZ   24064          // wz3 row stride (188*128); cols>=24000 written zero
#define TTG   3840000        // shorts per TT3 group (24000 rows x 160)
#define WZG   (256*NWZ)      // shorts per wz3 group
#define HROW  (256*160)      // shorts per H region

__device__ __forceinline__ unsigned short f2u(float f) {  // RNE f32->bf16
  unsigned x = __float_as_uint(f);
  x += 0x7FFFu + ((x >> 16) & 1u);
  return (unsigned short)(x >> 16);
}

typedef __attribute__((ext_vector_type(8))) short frag8;
typedef __attribute__((ext_vector_type(4))) float facc4;
typedef __attribute__((ext_vector_type(4))) unsigned uint4v;

__constant__ int c_zsel[6] = {2, 2, 2, 2, 0, 1};  // Z region per group (sh,st,pp = 0,1,2)
__constant__ int c_xsel[6] = {0, 0, 0, 1, 2, 2};
__constant__ int c_ysel[6] = {1, 1, 0, 1, 2, 2};
__constant__ int c_tx[10] = {0, 1, 1, 2, 2, 2, 3, 3, 3, 3};
__constant__ int c_ty[10] = {0, 0, 1, 0, 1, 2, 0, 1, 2, 3};

// ---------------- MLP split-K partials: P[m][ks][bn][160] ----------------
__global__ __launch_bounds__(256) void mlp_partial(
    const float* __restrict__ x,
    const float* __restrict__ W0, const float* __restrict__ W1, const float* __restrict__ W2,
    float* __restrict__ P)
{
  int m = blockIdx.x, bt = blockIdx.y, ks = blockIdx.z;
  const float* W = (m == 0) ? W0 : (m == 1) ? W1 : W2;
  int bn0 = bt * 32, k0 = ks * 128;
  __shared__ float xs[32][132];
  int tid = threadIdx.x;
  for (int e = 0; e < 4; ++e) {
    int l = e * 256 + tid;
    int row = l >> 5, c4 = l & 31;
    float4 v = *(const float4*)&x[(bn0 + row) * 1024 + k0 + c4 * 4];
    xs[row][c4 * 4 + 0] = v.x; xs[row][c4 * 4 + 1] = v.y;
    xs[row][c4 * 4 + 2] = v.z; xs[row][c4 * 4 + 3] = v.w;
  }
  __syncthreads();
  int tj = tid & 15, tt = tid >> 4, r = tt * 2;
  int dd[10];
  #pragma unroll
  for (int u = 0; u < 10; ++u) { int d = tj + 16 * u; dd[u] = d < 150 ? d : 149; }
  float a0[10], a1[10];
  #pragma unroll
  for (int u = 0; u < 10; ++u) { a0[u] = 0.f; a1[u] = 0.f; }
  for (int k = 0; k < 128; ++k) {
    float xa = xs[r][k], xb = xs[r + 1][k];
    const float* wr = W + (long long)(k0 + k) * 150;
    #pragma unroll
    for (int u = 0; u < 10; ++u) {
      float w = wr[dd[u]];
      a0[u] += xa * w; a1[u] += xb * w;
    }
  }
  float* Pb = P + (long long)(m * 8 + ks) * 256 * 160;
  #pragma unroll
  for (int u = 0; u < 10; ++u) {
    int d = tj + 16 * u;
    Pb[(bn0 + r) * 160 + d]     = a0[u];
    Pb[(bn0 + r + 1) * 160 + d] = a1[u];
  }
}

// ---------------- MLP reduce: H[m][bn][160] bf16 (pads exact zero) ----------------
__global__ __launch_bounds__(256) void mlp_reduce(
    const float* __restrict__ P,
    const float* __restrict__ B0, const float* __restrict__ B1, const float* __restrict__ B2,
    unsigned short* __restrict__ H)
{
  int o = blockIdx.x * 256 + threadIdx.x;     // < 3*256*160
  int d = o % 160;
  int bn = (o / 160) & 255;
  int m = o / (160 * 256);
  float v = 0.f;
  if (d < 150) {
    const float* Bv = (m == 0) ? B0 : (m == 1) ? B1 : B2;
    v = Bv[d];
    #pragma unroll
    for (int ks = 0; ks < 8; ++ks)
      v += P[((long long)(m * 8 + ks) * 256 + bn) * 160 + d];
    v = v > 0.f ? v : 0.1f * v;
  }
  H[o] = f2u(v);
}

// ------ TT3g[g][(j*160+i)][k] = bf16(T_g[i][k][j]); i,k pads zero; all 6 groups ------
struct TPtrs { const float* t[6]; };
__global__ __launch_bounds__(256) void tt_kernel(TPtrs tp, unsigned short* __restrict__ TT3)
{
  int i = blockIdx.x;                  // 0..159
  int ky = blockIdx.y % 5, jy = blockIdx.y / 5;
  int k0 = ky * 32, j0 = jy * 32;
  int g = blockIdx.z;
  const float* T = tp.t[g];
  unsigned short* TT = TT3 + (long long)g * TTG;
  __shared__ float tl[32][33];
  int tid = threadIdx.x;
  #pragma unroll
  for (int e = 0; e < 4; ++e) {
    int l = e * 256 + tid;
    int r = l >> 5, c = l & 31;
    float v = 0.f;
    if (i < 150 && k0 + r < 150 && j0 + c < 150)
      v = T[i * 22500 + (k0 + r) * 150 + (j0 + c)];
    tl[r][c] = v;
  }
  __syncthreads();
  #pragma unroll
  for (int e = 0; e < 4; ++e) {
    int l = e * 256 + tid;
    int rr = l >> 5, cc = l & 31;
    if (j0 + rr < 150)
      TT[(long long)((j0 + rr) * 160 + i) * 160 + k0 + cc] = f2u(tl[cc][rr]);
  }
}

// ---- wz3g[g][m][n] = sum_k Z_g[m,k]*TT3g[g][n][k]; grid (188, 2, 6), bf16 out ----
__global__ __launch_bounds__(256) void wz_gemm(
    const unsigned short* __restrict__ Hb, const unsigned short* __restrict__ TT3,
    unsigned short* __restrict__ wz3)
{
  constexpr int LR = 72;
  __shared__ unsigned short lA[128 * LR];
  __shared__ unsigned short lB[128 * LR];
  int g = blockIdx.z, tid = threadIdx.x;
  const unsigned short* Ab = Hb + c_zsel[g] * HROW + blockIdx.y * 128 * 160;
  const unsigned short* Bb = TT3 + (long long)g * TTG;
  int n0 = blockIdx.x * 128;
  int wave = tid >> 6, lane = tid & 63;
  int l15 = lane & 15, lq = lane >> 4;
  int mw = (wave & 1) * 64, nw = (wave >> 1) * 64;
  facc4 acc[4][4];
  #pragma unroll
  for (int i = 0; i < 4; ++i)
    #pragma unroll
    for (int j = 0; j < 4; ++j) acc[i][j] = (facc4){0.f, 0.f, 0.f, 0.f};
  for (int ch = 0; ch < 3; ++ch) {
    int k0 = ch << 6;
    int sh = (ch == 2) ? 2 : 3, upr = 1 << sh;
    for (int u = tid; u < 128 * upr; u += 256) {
      int row = u >> sh, off = (u & (upr - 1)) << 3;
      *(uint4*)&lA[row * LR + off] = *(const uint4*)&Ab[row * 160 + k0 + off];
    }
    for (int u = tid; u < 128 * upr; u += 256) {
      int row = u >> sh, off = (u & (upr - 1)) << 3;
      int gn = n0 + row;
      uint4 v; v.x = 0u; v.y = 0u; v.z = 0u; v.w = 0u;
      if (gn < 24000) v = *(const uint4*)&Bb[(long long)gn * 160 + k0 + off];
      *(uint4*)&lB[row * LR + off] = v;
    }
    __syncthreads();
    int nks = (ch == 2) ? 1 : 2;
    for (int ks = 0; ks < nks; ++ks) {
      int ko = (ks << 5) + (lq << 3);
      frag8 af[4], bfr[4];
      #pragma unroll
      for (int i = 0; i < 4; ++i) af[i] = *(const frag8*)&lA[(mw + i * 16 + l15) * LR + ko];
      #pragma unroll
      for (int j = 0; j < 4; ++j) bfr[j] = *(const frag8*)&lB[(nw + j * 16 + l15) * LR + ko];
      #pragma unroll
      for (int i = 0; i < 4; ++i)
        #pragma unroll
        for (int j = 0; j < 4; ++j)
          acc[i][j] = __builtin_amdgcn_mfma_f32_16x16x32_bf16(af[i], bfr[j], acc[i][j], 0, 0, 0);
    }
    __syncthreads();
  }
  unsigned short* C = wz3 + (long long)g * WZG;
  int mb = blockIdx.y * 128 + mw;
  #pragma unroll
  for (int i = 0; i < 4; ++i)
    #pragma unroll
    for (int r = 0; r < 4; ++r) {
      int m = mb + i * 16 + lq * 4 + r;
      #pragma unroll
      for (int j = 0; j < 4; ++j)
        C[(long long)m * NWZ + n0 + nw + j * 16 + l15] = f2u(acc[i][j][r]);
    }
}

// ---- fused tmp+s per z: W staged in LDS (23KB); X,Y frags direct from
//      L2-hot H; tmp in registers (swapped phase-1 + shfl repack); phase-2 in
//      yt-halves; upper-triangle epilogue. grid (1536) ----
struct SPtrs { float* p[6]; };
__global__ __launch_bounds__(256, 4) void tmps_gemm(
    const unsigned short* __restrict__ Hb, const unsigned short* __restrict__ wz3,
    SPtrs sp)
{
  __shared__ unsigned short Wsm[160 * 72];   // 23,040 B; wz rows j, per-chunk

  int z = blockIdx.x, tid = threadIdx.x;
  int g = z >> 8, bz = z & 255, b = bz >> 7;
  const unsigned short* Ab = Hb + c_xsel[g] * HROW + b * 128 * 160;  // X rows
  const unsigned short* Wb = wz3 + (long long)g * WZG + (long long)bz * NWZ;  // wz rows j
  int wave = tid >> 6, lane = tid & 63;
  int l15 = lane & 15, lq = lane >> 4;
  int X0 = wave * 32;                 // x-band per wave

  const unsigned short* Xr0 = Ab + (X0 + l15) * 160;
  const unsigned short* Xr1 = Ab + (X0 + 16 + l15) * 160;

  // ---------- phase 1 (swapped): accT[j-tile][x-tile] : D[j][x] = wz . X^T ----------
  facc4 accT[10][2];
  #pragma unroll
  for (int jt = 0; jt < 10; ++jt)
    #pragma unroll
    for (int xt = 0; xt < 2; ++xt) accT[jt][xt] = (facc4){0.f, 0.f, 0.f, 0.f};
  for (int ch = 0; ch < 3; ++ch) {
    int k0 = ch << 6;
    int sh = (ch == 2) ? 2 : 3, upr = 1 << sh;
    for (int u = tid; u < 160 * upr; u += 256) {
      int row = u >> sh, off = (u & (upr - 1)) << 3;
      uint4 v; v.x = 0u; v.y = 0u; v.z = 0u; v.w = 0u;
      if (row < 150) v = *(const uint4*)&Wb[row * 160 + k0 + off];
      *(uint4*)&Wsm[row * 72 + off] = v;
    }
    __syncthreads();
    int nks = (ch == 2) ? 1 : 2;
    for (int ks = 0; ks < nks; ++ks) {
      int ko = (ks << 5) + (lq << 3);
      frag8 bx0 = *(const frag8*)&Xr0[k0 + ko];
      frag8 bx1 = *(const frag8*)&Xr1[k0 + ko];
      #pragma unroll
      for (int jt = 0; jt < 10; ++jt) {
        frag8 aw = *(const frag8*)&Wsm[(jt * 16 + l15) * 72 + ko];
        accT[jt][0] = __builtin_amdgcn_mfma_f32_16x16x32_bf16(aw, bx0, accT[jt][0], 0, 0, 0);
        accT[jt][1] = __builtin_amdgcn_mfma_f32_16x16x32_bf16(aw, bx1, accT[jt][1], 0, 0, 0);
      }
    }
    __syncthreads();
  }

  // ---------- repack accT -> phase-2 A-frags (f2u + __shfl, no asm) ----------
  // accT[jt][xt] lane(lq',l15'): holds tmp[x = X0+16xt+l15'][j = 16jt+4lq'+r].
  // pA[xt][kb] lane(lq,l15) needs tmp[x = X0+16xt+l15][j = 32kb+8lq+e], e=0..7,
  // packed as words (e0,e1)(e2,e3)(e4,e5)(e6,e7).
  // word w source: register pk(r0,r1 | r2,r3) of jt-tile 2kb+(lq>=2), from
  // source lane 32*(lq&1) + 16*(w>=2) + l15.
  frag8 pA[2][5];
  {
    int s0 = ((lq & 1) << 5) + l15;
    int s2 = s0 + 16;
    bool lo = lq < 2;
    #pragma unroll
    for (int kb = 0; kb < 5; ++kb)
      #pragma unroll
      for (int xt = 0; xt < 2; ++xt) {
        unsigned w0l = (unsigned)f2u(accT[2 * kb][xt][0]) |
                       ((unsigned)f2u(accT[2 * kb][xt][1]) << 16);
        unsigned w1l = (unsigned)f2u(accT[2 * kb][xt][2]) |
                       ((unsigned)f2u(accT[2 * kb][xt][3]) << 16);
        unsigned w0h = (unsigned)f2u(accT[2 * kb + 1][xt][0]) |
                       ((unsigned)f2u(accT[2 * kb + 1][xt][1]) << 16);
        unsigned w1h = (unsigned)f2u(accT[2 * kb + 1][xt][2]) |
                       ((unsigned)f2u(accT[2 * kb + 1][xt][3]) << 16);
        unsigned a0 = __shfl(w0l, s0), b0 = __shfl(w0h, s0);
        unsigned a1 = __shfl(w1l, s0), b1 = __shfl(w1h, s0);
        unsigned a2 = __shfl(w0l, s2), b2 = __shfl(w0h, s2);
        unsigned a3 = __shfl(w1l, s2), b3 = __shfl(w1h, s2);
        uint4v uv;
        uv.x = lo ? a0 : b0;
        uv.y = lo ? a1 : b1;
        uv.z = lo ? a2 : b2;
        uv.w = lo ? a3 : b3;
        pA[xt][kb] = __builtin_bit_cast(frag8, uv);
      }
  }

  // ---------- phase 2 (yt-halves): s[x][y] = sum_j tmp[x][j] * Y[y][j] ----------
  const unsigned short* Yb = Hb + c_ysel[g] * HROW + b * 128 * 160;
  float* C = sp.p[g] + (long long)bz * 16384;
  for (int h = 0; h < 2; ++h) {
    facc4 acc2[2][4];
    #pragma unroll
    for (int xt = 0; xt < 2; ++xt)
      #pragma unroll
      for (int j = 0; j < 4; ++j) acc2[xt][j] = (facc4){0.f, 0.f, 0.f, 0.f};
    #pragma unroll
    for (int ks = 0; ks < 5; ++ks) {
      int ko = (ks << 5) + (lq << 3);
      #pragma unroll
      for (int j = 0; j < 4; ++j) {
        frag8 by = *(const frag8*)&Yb[((h * 4 + j) * 16 + l15) * 160 + ko];
        acc2[0][j] = __builtin_amdgcn_mfma_f32_16x16x32_bf16(pA[0][ks], by, acc2[0][j], 0, 0, 0);
        acc2[1][j] = __builtin_amdgcn_mfma_f32_16x16x32_bf16(pA[1][ks], by, acc2[1][j], 0, 0, 0);
      }
    }
    // epilogue: g0 full; g>=1 upper triangle (x<=y) only.
    // acc2 lane(q,c): x = X0 + xt*16 + 4q + r, y = (h*4+j)*16 + c.
    #pragma unroll
    for (int xt = 0; xt < 2; ++xt)
      #pragma unroll
      for (int r = 0; r < 4; ++r) {
        int x = X0 + xt * 16 + lq * 4 + r;
        #pragma unroll
        for (int j = 0; j < 4; ++j) {
          int y = (h * 4 + j) * 16 + l15;
          if (g == 0 || x <= y) C[x * 128 + y] = acc2[xt][j][r];
        }
      }
  }
}

// ---- sym_fill: out[z][x][y] = out[z][y][x] for y < x, out blocks 1..3.
//      grid (768, 10): blockIdx.x = grp*256 + bz, blockIdx.y = lower tile ----
__global__ __launch_bounds__(256) void sym_fill(float* __restrict__ out)
{
  int zb = blockIdx.x;
  int grp = zb >> 8, bz = zb & 255;
  int t = blockIdx.y;
  int x0 = c_tx[t] << 5, y0 = c_ty[t] << 5;    // x band >= y band
  float* S = out + (long long)(1 + grp) * OUTBLK + (long long)bz * 16384;
  __shared__ float tl[32][33];
  int tid = threadIdx.x;
  #pragma unroll
  for (int e = 0; e < 4; ++e) {
    int l = e * 256 + tid;
    int r = l >> 5, c = l & 31;
    tl[r][c] = S[(y0 + r) * 128 + x0 + c];     // s[y][x] (upper; diag garbage unused)
  }
  __syncthreads();
  #pragma unroll
  for (int e = 0; e < 4; ++e) {
    int l = e * 256 + tid;
    int rr = l >> 5, cc = l & 31;
    int x = x0 + rr, y = y0 + cc;
    if (x > y) S[x * 128 + y] = tl[cc][rr];
  }
}

// ---------- cop: out[b,x,y,z] = ss[g][b,z,min(x,y),max(x,y)]; grid (512,4,4) ----------
__global__ __launch_bounds__(256) void cop_kernel(
    const float* __restrict__ ss, float* __restrict__ out)
{
  int w0 = blockIdx.x << 5;
  int z0 = blockIdx.y << 5;
  int g  = blockIdx.z >> 1, b = blockIdx.z & 1;
  const float* sg = ss + (long long)g * OUTBLK;
  float* outp = out + (long long)(4 + g) * OUTBLK;
  __shared__ float tl[32][33];
  int tid = threadIdx.x;
  #pragma unroll
  for (int e = 0; e < 4; ++e) {
    int l = e * 256 + tid;
    int r = l >> 5, c = l & 31;
    int w = w0 + c;
    int xx = w >> 7, yy = w & 127;
    int sx = xx < yy ? xx : yy;
    int sy = xx < yy ? yy : xx;
    tl[r][c] = sg[(((b << 7) + z0 + r) << 14) + (sx << 7) + sy];
  }
  __syncthreads();
  #pragma unroll
  for (int e = 0; e < 4; ++e) {
    int l = e * 256 + tid;
    int rr = l >> 5, cc = l & 31;
    outp[(b << 21) + ((w0 + rr) << 7) + z0 + cc] = tl[cc][rr];
  }
}

extern "C" void kernel_launch(void* const* d_in, const int* in_sizes, int n_in,
                              void* d_out, int out_size, void* d_ws, size_t ws_size,
                              hipStream_t stream)
{
  const float* x   = (const float*)d_in[0];
  const float* Wsh = (const float*)d_in[1];
  const float* bsh = (const float*)d_in[2];
  const float* Wst = (const float*)d_in[3];
  const float* bst = (const float*)d_in[4];
  const float* Wp  = (const float*)d_in[5];
  const float* bp  = (const float*)d_in[6];
  TPtrs tp;
  tp.t[0] = (const float*)d_in[8];   // T_ph    (span_psh)
  tp.t[1] = (const float*)d_in[7];   // T_pt    (span_pst)
  tp.t[2] = (const float*)d_in[9];   // T_phsib
  tp.t[3] = (const float*)d_in[10];  // T_ptsib
  tp.t[4] = (const float*)d_in[11];  // T_phcop
  tp.t[5] = (const float*)d_in[12];  // T_ptcop
  float* out = (float*)d_out;
  char* wsb = (char*)d_ws;

  // ws layout (bytes): H 245,760 | TT3g 46,080,000 | wz3g 73,924,608
  // P (7.9MB) aliases wz3g (dead before wz writes); ss (33.6MB) aliases TT3g
  // (TT3 fully consumed by wz_gemm before tmps_gemm writes ss).
  unsigned short* Hb   = (unsigned short*)(wsb);
  unsigned short* TT3  = (unsigned short*)(wsb + 245760);
  unsigned short* wz3  = (unsigned short*)(wsb + 46325760);
  float* P  = (float*)wz3;
  float* ss = (float*)TT3;

  SPtrs sp;
  sp.p[0] = out + 0LL * OUTBLK;
  sp.p[1] = out + 1LL * OUTBLK;
  sp.p[2] = out + 2LL * OUTBLK;
  sp.p[3] = out + 3LL * OUTBLK;
  sp.p[4] = ss;
  sp.p[5] = ss + OUTBLK;

  mlp_partial<<<dim3(3, 8, 8),    256, 0, stream>>>(x, Wsh, Wst, Wp, P);
  mlp_reduce <<<dim3(480),        256, 0, stream>>>(P, bsh, bst, bp, Hb);
  tt_kernel  <<<dim3(160, 25, 6), 256, 0, stream>>>(tp, TT3);
  wz_gemm    <<<dim3(188, 2, 6),  256, 0, stream>>>(Hb, TT3, wz3);
  tmps_gemm  <<<dim3(1536),       256, 0, stream>>>(Hb, wz3, sp);
  sym_fill   <<<dim3(768, 10),    256, 0, stream>>>(out);
  cop_kernel <<<dim3(512, 4, 4),  256, 0, stream>>>(ss, out);
}

// Round 8
// 362.381 us; speedup vs baseline: 1.0213x; 1.0081x over previous
//
#include <hip/hip_runtime.h>

// SRLSecondOrderScorer: B=2, N=128, D_IN=1024, D=150. Inputs f32, outputs f32.
// Round 13: r12 with the W-staging coverage bug fixed (20 uint4/row, not 10 —
// shorts [80,160) were stale -> NaN) and launch_bounds(256,3) (LDS caps at 3
// blocks/CU; the (256,4) reg-cap was pure spill risk). One barrier per block.
// Chain per group g: TT3g[g][(j*160+i)][k] = bf16(T_g[i][k][j])
//   wz3g[g][bz][j*160+i] = sum_k Z[bz,k]*TT3                     (MFMA GEMM)
//   tmp[x][j]            = sum_i X[b,x,i]*wz3     (in-register, fused)
//   s[g][bz][x][y]       = sum_j tmp*Y[b,y,j]     (upper-tri for g>=1;
//                                                  sym_fill mirrors g=1..3)
// H rows padded to 160 with exact zeros => all K-padding inert.

#define DD    150
#define KP    160
#define OUTBLK 4194304       // 2*128^3 floats
#define NWZ   24064          // wz3 row stride (188*128); cols>=24000 written zero
#define TTG   3840000        // shorts per TT3 group (24000 rows x 160)
#define WZG   (256*NWZ)      // shorts per wz3 group
#define HROW  (256*160)      // shorts per H region
#define WLD   164            // Wsm row stride (328B -> spread bank pattern)

__device__ __forceinline__ unsigned short f2u(float f) {  // RNE f32->bf16
  unsigned x = __float_as_uint(f);
  x += 0x7FFFu + ((x >> 16) & 1u);
  return (unsigned short)(x >> 16);
}

typedef __attribute__((ext_vector_type(8))) short frag8;
typedef __attribute__((ext_vector_type(4))) float facc4;
typedef __attribute__((ext_vector_type(4))) unsigned uint4v;

__constant__ int c_zsel[6] = {2, 2, 2, 2, 0, 1};  // Z region per group (sh,st,pp = 0,1,2)
__constant__ int c_xsel[6] = {0, 0, 0, 1, 2, 2};
__constant__ int c_ysel[6] = {1, 1, 0, 1, 2, 2};
__constant__ int c_tx[10] = {0, 1, 1, 2, 2, 2, 3, 3, 3, 3};
__constant__ int c_ty[10] = {0, 0, 1, 0, 1, 2, 0, 1, 2, 3};

// ---------------- MLP split-K partials: P[m][ks][bn][160] ----------------
__global__ __launch_bounds__(256) void mlp_partial(
    const float* __restrict__ x,
    const float* __restrict__ W0, const float* __restrict__ W1, const float* __restrict__ W2,
    float* __restrict__ P)
{
  int m = blockIdx.x, bt = blockIdx.y, ks = blockIdx.z;
  const float* W = (m == 0) ? W0 : (m == 1) ? W1 : W2;
  int bn0 = bt * 32, k0 = ks * 128;
  __shared__ float xs[32][132];
  int tid = threadIdx.x;
  for (int e = 0; e < 4; ++e) {
    int l = e * 256 + tid;
    int row = l >> 5, c4 = l & 31;
    float4 v = *(const float4*)&x[(bn0 + row) * 1024 + k0 + c4 * 4];
    xs[row][c4 * 4 + 0] = v.x; xs[row][c4 * 4 + 1] = v.y;
    xs[row][c4 * 4 + 2] = v.z; xs[row][c4 * 4 + 3] = v.w;
  }
  __syncthreads();
  int tj = tid & 15, tt = tid >> 4, r = tt * 2;
  int dd[10];
  #pragma unroll
  for (int u = 0; u < 10; ++u) { int d = tj + 16 * u; dd[u] = d < 150 ? d : 149; }
  float a0[10], a1[10];
  #pragma unroll
  for (int u = 0; u < 10; ++u) { a0[u] = 0.f; a1[u] = 0.f; }
  for (int k = 0; k < 128; ++k) {
    float xa = xs[r][k], xb = xs[r + 1][k];
    const float* wr = W + (long long)(k0 + k) * 150;
    #pragma unroll
    for (int u = 0; u < 10; ++u) {
      float w = wr[dd[u]];
      a0[u] += xa * w; a1[u] += xb * w;
    }
  }
  float* Pb = P + (long long)(m * 8 + ks) * 256 * 160;
  #pragma unroll
  for (int u = 0; u < 10; ++u) {
    int d = tj + 16 * u;
    Pb[(bn0 + r) * 160 + d]     = a0[u];
    Pb[(bn0 + r + 1) * 160 + d] = a1[u];
  }
}

// ---------------- MLP reduce: H[m][bn][160] bf16 (pads exact zero) ----------------
__global__ __launch_bounds__(256) void mlp_reduce(
    const float* __restrict__ P,
    const float* __restrict__ B0, const float* __restrict__ B1, const float* __restrict__ B2,
    unsigned short* __restrict__ H)
{
  int o = blockIdx.x * 256 + threadIdx.x;     // < 3*256*160
  int d = o % 160;
  int bn = (o / 160) & 255;
  int m = o / (160 * 256);
  float v = 0.f;
  if (d < 150) {
    const float* Bv = (m == 0) ? B0 : (m == 1) ? B1 : B2;
    v = Bv[d];
    #pragma unroll
    for (int ks = 0; ks < 8; ++ks)
      v += P[((long long)(m * 8 + ks) * 256 + bn) * 160 + d];
    v = v > 0.f ? v : 0.1f * v;
  }
  H[o] = f2u(v);
}

// ------ TT3g[g][(j*160+i)][k] = bf16(T_g[i][k][j]); i,k pads zero; all 6 groups ------
struct TPtrs { const float* t[6]; };
__global__ __launch_bounds__(256) void tt_kernel(TPtrs tp, unsigned short* __restrict__ TT3)
{
  int i = blockIdx.x;                  // 0..159
  int ky = blockIdx.y % 5, jy = blockIdx.y / 5;
  int k0 = ky * 32, j0 = jy * 32;
  int g = blockIdx.z;
  const float* T = tp.t[g];
  unsigned short* TT = TT3 + (long long)g * TTG;
  __shared__ float tl[32][33];
  int tid = threadIdx.x;
  #pragma unroll
  for (int e = 0; e < 4; ++e) {
    int l = e * 256 + tid;
    int r = l >> 5, c = l & 31;
    float v = 0.f;
    if (i < 150 && k0 + r < 150 && j0 + c < 150)
      v = T[i * 22500 + (k0 + r) * 150 + (j0 + c)];
    tl[r][c] = v;
  }
  __syncthreads();
  #pragma unroll
  for (int e = 0; e < 4; ++e) {
    int l = e * 256 + tid;
    int rr = l >> 5, cc = l & 31;
    if (j0 + rr < 150)
      TT[(long long)((j0 + rr) * 160 + i) * 160 + k0 + cc] = f2u(tl[cc][rr]);
  }
}

// ---- wz3g[g][m][n] = sum_k Z_g[m,k]*TT3g[g][n][k]; grid (188, 2, 6), bf16 out ----
__global__ __launch_bounds__(256) void wz_gemm(
    const unsigned short* __restrict__ Hb, const unsigned short* __restrict__ TT3,
    unsigned short* __restrict__ wz3)
{
  constexpr int LR = 72;
  __shared__ unsigned short lA[128 * LR];
  __shared__ unsigned short lB[128 * LR];
  int g = blockIdx.z, tid = threadIdx.x;
  const unsigned short* Ab = Hb + c_zsel[g] * HROW + blockIdx.y * 128 * 160;
  const unsigned short* Bb = TT3 + (long long)g * TTG;
  int n0 = blockIdx.x * 128;
  int wave = tid >> 6, lane = tid & 63;
  int l15 = lane & 15, lq = lane >> 4;
  int mw = (wave & 1) * 64, nw = (wave >> 1) * 64;
  facc4 acc[4][4];
  #pragma unroll
  for (int i = 0; i < 4; ++i)
    #pragma unroll
    for (int j = 0; j < 4; ++j) acc[i][j] = (facc4){0.f, 0.f, 0.f, 0.f};
  for (int ch = 0; ch < 3; ++ch) {
    int k0 = ch << 6;
    int sh = (ch == 2) ? 2 : 3, upr = 1 << sh;
    for (int u = tid; u < 128 * upr; u += 256) {
      int row = u >> sh, off = (u & (upr - 1)) << 3;
      *(uint4*)&lA[row * LR + off] = *(const uint4*)&Ab[row * 160 + k0 + off];
    }
    for (int u = tid; u < 128 * upr; u += 256) {
      int row = u >> sh, off = (u & (upr - 1)) << 3;
      int gn = n0 + row;
      uint4 v; v.x = 0u; v.y = 0u; v.z = 0u; v.w = 0u;
      if (gn < 24000) v = *(const uint4*)&Bb[(long long)gn * 160 + k0 + off];
      *(uint4*)&lB[row * LR + off] = v;
    }
    __syncthreads();
    int nks = (ch == 2) ? 1 : 2;
    for (int ks = 0; ks < nks; ++ks) {
      int ko = (ks << 5) + (lq << 3);
      frag8 af[4], bfr[4];
      #pragma unroll
      for (int i = 0; i < 4; ++i) af[i] = *(const frag8*)&lA[(mw + i * 16 + l15) * LR + ko];
      #pragma unroll
      for (int j = 0; j < 4; ++j) bfr[j] = *(const frag8*)&lB[(nw + j * 16 + l15) * LR + ko];
      #pragma unroll
      for (int i = 0; i < 4; ++i)
        #pragma unroll
        for (int j = 0; j < 4; ++j)
          acc[i][j] = __builtin_amdgcn_mfma_f32_16x16x32_bf16(af[i], bfr[j], acc[i][j], 0, 0, 0);
    }
    __syncthreads();
  }
  unsigned short* C = wz3 + (long long)g * WZG;
  int mb = blockIdx.y * 128 + mw;
  #pragma unroll
  for (int i = 0; i < 4; ++i)
    #pragma unroll
    for (int r = 0; r < 4; ++r) {
      int m = mb + i * 16 + lq * 4 + r;
      #pragma unroll
      for (int j = 0; j < 4; ++j)
        C[(long long)m * NWZ + n0 + nw + j * 16 + l15] = f2u(acc[i][j][r]);
    }
}

// ---- fused tmp+s per z: whole W staged ONCE in LDS (52.5KB, 3 blocks/CU),
//      ONE barrier; X,Y direct from L2-hot H; tmp in registers (swapped
//      phase-1 + shfl repack); upper-triangle epilogue. grid (1536) ----
struct SPtrs { float* p[6]; };
__global__ __launch_bounds__(256, 3) void tmps_gemm(
    const unsigned short* __restrict__ Hb, const unsigned short* __restrict__ wz3,
    SPtrs sp)
{
  __shared__ unsigned short Wsm[160 * WLD];   // 52,480 B

  int z = blockIdx.x, tid = threadIdx.x;
  int g = z >> 8, bz = z & 255, b = bz >> 7;
  const unsigned short* Ab = Hb + c_xsel[g] * HROW + b * 128 * 160;  // X rows
  const unsigned short* Wb = wz3 + (long long)g * WZG + (long long)bz * NWZ;  // wz rows j
  int wave = tid >> 6, lane = tid & 63;
  int l15 = lane & 15, lq = lane >> 4;
  int X0 = wave * 32;                 // x-band per wave

  // ---------- stage whole W[160][160] (rows >=150 zero): 20 uint4 per row ----------
  for (int u = tid; u < 3200; u += 256) {
    int row = u / 20, q = u % 20;
    uint4 v; v.x = 0u; v.y = 0u; v.z = 0u; v.w = 0u;
    if (row < 150) v = *(const uint4*)&Wb[row * 160 + q * 8];
    *(uint4*)&Wsm[row * WLD + q * 8] = v;
  }
  __syncthreads();                     // the ONLY barrier in this kernel

  const unsigned short* Xr0 = Ab + (X0 + l15) * 160;
  const unsigned short* Xr1 = Ab + (X0 + 16 + l15) * 160;

  // ---------- phase 1 (swapped): accT[j-tile][x-tile] : D[j][x] = wz . X^T ----------
  facc4 accT[10][2];
  #pragma unroll
  for (int jt = 0; jt < 10; ++jt)
    #pragma unroll
    for (int xt = 0; xt < 2; ++xt) accT[jt][xt] = (facc4){0.f, 0.f, 0.f, 0.f};
  #pragma unroll
  for (int ks = 0; ks < 5; ++ks) {
    int ko = ks * 32 + (lq << 3);
    frag8 bx0 = *(const frag8*)&Xr0[ko];
    frag8 bx1 = *(const frag8*)&Xr1[ko];
    #pragma unroll
    for (int jt = 0; jt < 10; ++jt) {
      frag8 aw = *(const frag8*)&Wsm[(jt * 16 + l15) * WLD + ko];
      accT[jt][0] = __builtin_amdgcn_mfma_f32_16x16x32_bf16(aw, bx0, accT[jt][0], 0, 0, 0);
      accT[jt][1] = __builtin_amdgcn_mfma_f32_16x16x32_bf16(aw, bx1, accT[jt][1], 0, 0, 0);
    }
  }

  // ---------- repack accT -> phase-2 A-frags (f2u + __shfl, no asm) ----------
  // accT[jt][xt] lane(lq',l15'): holds tmp[x = X0+16xt+l15'][j = 16jt+4lq'+r].
  // pA[xt][kb] lane(lq,l15) needs tmp[x = X0+16xt+l15][j = 32kb+8lq+e], e=0..7,
  // packed as words (e0,e1)(e2,e3)(e4,e5)(e6,e7).
  // word w source: register pk(r0,r1 | r2,r3) of jt-tile 2kb+(lq>=2), from
  // source lane 32*(lq&1) + 16*(w>=2) + l15.
  frag8 pA[2][5];
  {
    int s0 = ((lq & 1) << 5) + l15;
    int s2 = s0 + 16;
    bool lo = lq < 2;
    #pragma unroll
    for (int kb = 0; kb < 5; ++kb)
      #pragma unroll
      for (int xt = 0; xt < 2; ++xt) {
        unsigned w0l = (unsigned)f2u(accT[2 * kb][xt][0]) |
                       ((unsigned)f2u(accT[2 * kb][xt][1]) << 16);
        unsigned w1l = (unsigned)f2u(accT[2 * kb][xt][2]) |
                       ((unsigned)f2u(accT[2 * kb][xt][3]) << 16);
        unsigned w0h = (unsigned)f2u(accT[2 * kb + 1][xt][0]) |
                       ((unsigned)f2u(accT[2 * kb + 1][xt][1]) << 16);
        unsigned w1h = (unsigned)f2u(accT[2 * kb + 1][xt][2]) |
                       ((unsigned)f2u(accT[2 * kb + 1][xt][3]) << 16);
        unsigned a0 = __shfl(w0l, s0), b0 = __shfl(w0h, s0);
        unsigned a1 = __shfl(w1l, s0), b1 = __shfl(w1h, s0);
        unsigned a2 = __shfl(w0l, s2), b2 = __shfl(w0h, s2);
        unsigned a3 = __shfl(w1l, s2), b3 = __shfl(w1h, s2);
        uint4v uv;
        uv.x = lo ? a0 : b0;
        uv.y = lo ? a1 : b1;
        uv.z = lo ? a2 : b2;
        uv.w = lo ? a3 : b3;
        pA[xt][kb] = __builtin_bit_cast(frag8, uv);
      }
  }

  // ---------- phase 2 (yt-halves): s[x][y] = sum_j tmp[x][j] * Y[y][j] ----------
  const unsigned short* Yb = Hb + c_ysel[g] * HROW + b * 128 * 160;
  float* C = sp.p[g] + (long long)bz * 16384;
  for (int h = 0; h < 2; ++h) {
    facc4 acc2[2][4];
    #pragma unroll
    for (int xt = 0; xt < 2; ++xt)
      #pragma unroll
      for (int j = 0; j < 4; ++j) acc2[xt][j] = (facc4){0.f, 0.f, 0.f, 0.f};
    #pragma unroll
    for (int ks = 0; ks < 5; ++ks) {
      int ko = (ks << 5) + (lq << 3);
      #pragma unroll
      for (int j = 0; j < 4; ++j) {
        frag8 by = *(const frag8*)&Yb[((h * 4 + j) * 16 + l15) * 160 + ko];
        acc2[0][j] = __builtin_amdgcn_mfma_f32_16x16x32_bf16(pA[0][ks], by, acc2[0][j], 0, 0, 0);
        acc2[1][j] = __builtin_amdgcn_mfma_f32_16x16x32_bf16(pA[1][ks], by, acc2[1][j], 0, 0, 0);
      }
    }
    // epilogue: g0 full; g>=1 upper triangle (x<=y) only.
    // acc2 lane(q,c): x = X0 + xt*16 + 4q + r, y = (h*4+j)*16 + c.
    #pragma unroll
    for (int xt = 0; xt < 2; ++xt)
      #pragma unroll
      for (int r = 0; r < 4; ++r) {
        int x = X0 + xt * 16 + lq * 4 + r;
        #pragma unroll
        for (int j = 0; j < 4; ++j) {
          int y = (h * 4 + j) * 16 + l15;
          if (g == 0 || x <= y) C[x * 128 + y] = acc2[xt][j][r];
        }
      }
  }
}

// ---- sym_fill: out[z][x][y] = out[z][y][x] for y < x, out blocks 1..3.
//      grid (768, 10): blockIdx.x = grp*256 + bz, blockIdx.y = lower tile ----
__global__ __launch_bounds__(256) void sym_fill(float* __restrict__ out)
{
  int zb = blockIdx.x;
  int grp = zb >> 8, bz = zb & 255;
  int t = blockIdx.y;
  int x0 = c_tx[t] << 5, y0 = c_ty[t] << 5;    // x band >= y band
  float* S = out + (long long)(1 + grp) * OUTBLK + (long long)bz * 16384;
  __shared__ float tl[32][33];
  int tid = threadIdx.x;
  #pragma unroll
  for (int e = 0; e < 4; ++e) {
    int l = e * 256 + tid;
    int r = l >> 5, c = l & 31;
    tl[r][c] = S[(y0 + r) * 128 + x0 + c];     // s[y][x] (upper; diag garbage unused)
  }
  __syncthreads();
  #pragma unroll
  for (int e = 0; e < 4; ++e) {
    int l = e * 256 + tid;
    int rr = l >> 5, cc = l & 31;
    int x = x0 + rr, y = y0 + cc;
    if (x > y) S[x * 128 + y] = tl[cc][rr];
  }
}

// ---------- cop: out[b,x,y,z] = ss[g][b,z,min(x,y),max(x,y)]; grid (512,4,4) ----------
__global__ __launch_bounds__(256) void cop_kernel(
    const float* __restrict__ ss, float* __restrict__ out)
{
  int w0 = blockIdx.x << 5;
  int z0 = blockIdx.y << 5;
  int g  = blockIdx.z >> 1, b = blockIdx.z & 1;
  const float* sg = ss + (long long)g * OUTBLK;
  float* outp = out + (long long)(4 + g) * OUTBLK;
  __shared__ float tl[32][33];
  int tid = threadIdx.x;
  #pragma unroll
  for (int e = 0; e < 4; ++e) {
    int l = e * 256 + tid;
    int r = l >> 5, c = l & 31;
    int w = w0 + c;
    int xx = w >> 7, yy = w & 127;
    int sx = xx < yy ? xx : yy;
    int sy = xx < yy ? yy : xx;
    tl[r][c] = sg[(((b << 7) + z0 + r) << 14) + (sx << 7) + sy];
  }
  __syncthreads();
  #pragma unroll
  for (int e = 0; e < 4; ++e) {
    int l = e * 256 + tid;
    int rr = l >> 5, cc = l & 31;
    outp[(b << 21) + ((w0 + rr) << 7) + z0 + cc] = tl[cc][rr];
  }
}

extern "C" void kernel_launch(void* const* d_in, const int* in_sizes, int n_in,
                              void* d_out, int out_size, void* d_ws, size_t ws_size,
                              hipStream_t stream)
{
  const float* x   = (const float*)d_in[0];
  const float* Wsh = (const float*)d_in[1];
  const float* bsh = (const float*)d_in[2];
  const float* Wst = (const float*)d_in[3];
  const float* bst = (const float*)d_in[4];
  const float* Wp  = (const float*)d_in[5];
  const float* bp  = (const float*)d_in[6];
  TPtrs tp;
  tp.t[0] = (const float*)d_in[8];   // T_ph    (span_psh)
  tp.t[1] = (const float*)d_in[7];   // T_pt    (span_pst)
  tp.t[2] = (const float*)d_in[9];   // T_phsib
  tp.t[3] = (const float*)d_in[10];  // T_ptsib
  tp.t[4] = (const float*)d_in[11];  // T_phcop
  tp.t[5] = (const float*)d_in[12];  // T_ptcop
  float* out = (float*)d_out;
  char* wsb = (char*)d_ws;

  // ws layout (bytes): H 245,760 | TT3g 46,080,000 | wz3g 73,924,608
  // P (7.9MB) aliases wz3g (dead before wz writes); ss (33.6MB) aliases TT3g
  // (TT3 fully consumed by wz_gemm before tmps_gemm writes ss).
  unsigned short* Hb   = (unsigned short*)(wsb);
  unsigned short* TT3  = (unsigned short*)(wsb + 245760);
  unsigned short* wz3  = (unsigned short*)(wsb + 46325760);
  float* P  = (float*)wz3;
  float* ss = (float*)TT3;

  SPtrs sp;
  sp.p[0] = out + 0LL * OUTBLK;
  sp.p[1] = out + 1LL * OUTBLK;
  sp.p[2] = out + 2LL * OUTBLK;
  sp.p[3] = out + 3LL * OUTBLK;
  sp.p[4] = ss;
  sp.p[5] = ss + OUTBLK;

  mlp_partial<<<dim3(3, 8, 8),    256, 0, stream>>>(x, Wsh, Wst, Wp, P);
  mlp_reduce <<<dim3(480),        256, 0, stream>>>(P, bsh, bst, bp, Hb);
  tt_kernel  <<<dim3(160, 25, 6), 256, 0, stream>>>(tp, TT3);
  wz_gemm    <<<dim3(188, 2, 6),  256, 0, stream>>>(Hb, TT3, wz3);
  tmps_gemm  <<<dim3(1536),       256, 0, stream>>>(Hb, wz3, sp);
  sym_fill   <<<dim3(768, 10),    256, 0, stream>>>(out);
  cop_kernel <<<dim3(512, 4, 4),  256, 0, stream>>>(ss, out);
}

// Round 9
// 348.998 us; speedup vs baseline: 1.0605x; 1.0383x over previous
//
#include <hip/hip_runtime.h>

// SRLSecondOrderScorer: B=2, N=128, D_IN=1024, D=150. Inputs f32, outputs f32.
// Round 14: r13 + triu_sym folded back into tmps_gemm epilogue via LDS union
// (Wsm dead after phase 1 -> overlay float sq[128][65], 33.3KB <= 52.5KB).
// sym_fill kernel deleted. 6 launches total.
// Chain per group g: TT3g[g][(j*160+i)][k] = bf16(T_g[i][k][j])
//   wz3g[g][bz][j*160+i] = sum_k Z[bz,k]*TT3                     (MFMA GEMM)
//   tmp[x][j]            = sum_i X[b,x,i]*wz3     (in-register, fused)
//   s[g][bz][x][y]       = sum_j tmp*Y[b,y,j]     (+in-kernel sym g=1..3,
//                                                  upper-tri only for g=4,5)
// H rows padded to 160 with exact zeros => all K-padding inert.

#define DD    150
#define KP    160
#define OUTBLK 4194304       // 2*128^3 floats
#define NWZ   24064          // wz3 row stride (188*128); cols>=24000 written zero
#define TTG   3840000        // shorts per TT3 group (24000 rows x 160)
#define WZG   (256*NWZ)      // shorts per wz3 group
#define HROW  (256*160)      // shorts per H region
#define WLD   164            // Wsm row stride (328B -> spread bank pattern)

__device__ __forceinline__ unsigned short f2u(float f) {  // RNE f32->bf16
  unsigned x = __float_as_uint(f);
  x += 0x7FFFu + ((x >> 16) & 1u);
  return (unsigned short)(x >> 16);
}

typedef __attribute__((ext_vector_type(8))) short frag8;
typedef __attribute__((ext_vector_type(4))) float facc4;
typedef __attribute__((ext_vector_type(4))) unsigned uint4v;

__constant__ int c_zsel[6] = {2, 2, 2, 2, 0, 1};  // Z region per group (sh,st,pp = 0,1,2)
__constant__ int c_xsel[6] = {0, 0, 0, 1, 2, 2};
__constant__ int c_ysel[6] = {1, 1, 0, 1, 2, 2};

// ---------------- MLP split-K partials: P[m][ks][bn][160] ----------------
__global__ __launch_bounds__(256) void mlp_partial(
    const float* __restrict__ x,
    const float* __restrict__ W0, const float* __restrict__ W1, const float* __restrict__ W2,
    float* __restrict__ P)
{
  int m = blockIdx.x, bt = blockIdx.y, ks = blockIdx.z;
  const float* W = (m == 0) ? W0 : (m == 1) ? W1 : W2;
  int bn0 = bt * 32, k0 = ks * 128;
  __shared__ float xs[32][132];
  int tid = threadIdx.x;
  for (int e = 0; e < 4; ++e) {
    int l = e * 256 + tid;
    int row = l >> 5, c4 = l & 31;
    float4 v = *(const float4*)&x[(bn0 + row) * 1024 + k0 + c4 * 4];
    xs[row][c4 * 4 + 0] = v.x; xs[row][c4 * 4 + 1] = v.y;
    xs[row][c4 * 4 + 2] = v.z; xs[row][c4 * 4 + 3] = v.w;
  }
  __syncthreads();
  int tj = tid & 15, tt = tid >> 4, r = tt * 2;
  int dd[10];
  #pragma unroll
  for (int u = 0; u < 10; ++u) { int d = tj + 16 * u; dd[u] = d < 150 ? d : 149; }
  float a0[10], a1[10];
  #pragma unroll
  for (int u = 0; u < 10; ++u) { a0[u] = 0.f; a1[u] = 0.f; }
  for (int k = 0; k < 128; ++k) {
    float xa = xs[r][k], xb = xs[r + 1][k];
    const float* wr = W + (long long)(k0 + k) * 150;
    #pragma unroll
    for (int u = 0; u < 10; ++u) {
      float w = wr[dd[u]];
      a0[u] += xa * w; a1[u] += xb * w;
    }
  }
  float* Pb = P + (long long)(m * 8 + ks) * 256 * 160;
  #pragma unroll
  for (int u = 0; u < 10; ++u) {
    int d = tj + 16 * u;
    Pb[(bn0 + r) * 160 + d]     = a0[u];
    Pb[(bn0 + r + 1) * 160 + d] = a1[u];
  }
}

// ---------------- MLP reduce: H[m][bn][160] bf16 (pads exact zero) ----------------
__global__ __launch_bounds__(256) void mlp_reduce(
    const float* __restrict__ P,
    const float* __restrict__ B0, const float* __restrict__ B1, const float* __restrict__ B2,
    unsigned short* __restrict__ H)
{
  int o = blockIdx.x * 256 + threadIdx.x;     // < 3*256*160
  int d = o % 160;
  int bn = (o / 160) & 255;
  int m = o / (160 * 256);
  float v = 0.f;
  if (d < 150) {
    const float* Bv = (m == 0) ? B0 : (m == 1) ? B1 : B2;
    v = Bv[d];
    #pragma unroll
    for (int ks = 0; ks < 8; ++ks)
      v += P[((long long)(m * 8 + ks) * 256 + bn) * 160 + d];
    v = v > 0.f ? v : 0.1f * v;
  }
  H[o] = f2u(v);
}

// ------ TT3g[g][(j*160+i)][k] = bf16(T_g[i][k][j]); i,k pads zero; all 6 groups ------
struct TPtrs { const float* t[6]; };
__global__ __launch_bounds__(256) void tt_kernel(TPtrs tp, unsigned short* __restrict__ TT3)
{
  int i = blockIdx.x;                  // 0..159
  int ky = blockIdx.y % 5, jy = blockIdx.y / 5;
  int k0 = ky * 32, j0 = jy * 32;
  int g = blockIdx.z;
  const float* T = tp.t[g];
  unsigned short* TT = TT3 + (long long)g * TTG;
  __shared__ float tl[32][33];
  int tid = threadIdx.x;
  #pragma unroll
  for (int e = 0; e < 4; ++e) {
    int l = e * 256 + tid;
    int r = l >> 5, c = l & 31;
    float v = 0.f;
    if (i < 150 && k0 + r < 150 && j0 + c < 150)
      v = T[i * 22500 + (k0 + r) * 150 + (j0 + c)];
    tl[r][c] = v;
  }
  __syncthreads();
  #pragma unroll
  for (int e = 0; e < 4; ++e) {
    int l = e * 256 + tid;
    int rr = l >> 5, cc = l & 31;
    if (j0 + rr < 150)
      TT[(long long)((j0 + rr) * 160 + i) * 160 + k0 + cc] = f2u(tl[cc][rr]);
  }
}

// ---- wz3g[g][m][n] = sum_k Z_g[m,k]*TT3g[g][n][k]; grid (188, 2, 6), bf16 out ----
__global__ __launch_bounds__(256) void wz_gemm(
    const unsigned short* __restrict__ Hb, const unsigned short* __restrict__ TT3,
    unsigned short* __restrict__ wz3)
{
  constexpr int LR = 72;
  __shared__ unsigned short lA[128 * LR];
  __shared__ unsigned short lB[128 * LR];
  int g = blockIdx.z, tid = threadIdx.x;
  const unsigned short* Ab = Hb + c_zsel[g] * HROW + blockIdx.y * 128 * 160;
  const unsigned short* Bb = TT3 + (long long)g * TTG;
  int n0 = blockIdx.x * 128;
  int wave = tid >> 6, lane = tid & 63;
  int l15 = lane & 15, lq = lane >> 4;
  int mw = (wave & 1) * 64, nw = (wave >> 1) * 64;
  facc4 acc[4][4];
  #pragma unroll
  for (int i = 0; i < 4; ++i)
    #pragma unroll
    for (int j = 0; j < 4; ++j) acc[i][j] = (facc4){0.f, 0.f, 0.f, 0.f};
  for (int ch = 0; ch < 3; ++ch) {
    int k0 = ch << 6;
    int sh = (ch == 2) ? 2 : 3, upr = 1 << sh;
    for (int u = tid; u < 128 * upr; u += 256) {
      int row = u >> sh, off = (u & (upr - 1)) << 3;
      *(uint4*)&lA[row * LR + off] = *(const uint4*)&Ab[row * 160 + k0 + off];
    }
    for (int u = tid; u < 128 * upr; u += 256) {
      int row = u >> sh, off = (u & (upr - 1)) << 3;
      int gn = n0 + row;
      uint4 v; v.x = 0u; v.y = 0u; v.z = 0u; v.w = 0u;
      if (gn < 24000) v = *(const uint4*)&Bb[(long long)gn * 160 + k0 + off];
      *(uint4*)&lB[row * LR + off] = v;
    }
    __syncthreads();
    int nks = (ch == 2) ? 1 : 2;
    for (int ks = 0; ks < nks; ++ks) {
      int ko = (ks << 5) + (lq << 3);
      frag8 af[4], bfr[4];
      #pragma unroll
      for (int i = 0; i < 4; ++i) af[i] = *(const frag8*)&lA[(mw + i * 16 + l15) * LR + ko];
      #pragma unroll
      for (int j = 0; j < 4; ++j) bfr[j] = *(const frag8*)&lB[(nw + j * 16 + l15) * LR + ko];
      #pragma unroll
      for (int i = 0; i < 4; ++i)
        #pragma unroll
        for (int j = 0; j < 4; ++j)
          acc[i][j] = __builtin_amdgcn_mfma_f32_16x16x32_bf16(af[i], bfr[j], acc[i][j], 0, 0, 0);
    }
    __syncthreads();
  }
  unsigned short* C = wz3 + (long long)g * WZG;
  int mb = blockIdx.y * 128 + mw;
  #pragma unroll
  for (int i = 0; i < 4; ++i)
    #pragma unroll
    for (int r = 0; r < 4; ++r) {
      int m = mb + i * 16 + lq * 4 + r;
      #pragma unroll
      for (int j = 0; j < 4; ++j)
        C[(long long)m * NWZ + n0 + nw + j * 16 + l15] = f2u(acc[i][j][r]);
    }
}

// ---- fused tmp+s per z: whole W staged ONCE in LDS (52.5KB union, 3 blk/CU);
//      X,Y direct from L2-hot H; tmp in registers; sym fused via sq overlay
//      (Wsm dead after phase 1). grid (1536) ----
struct SPtrs { float* p[6]; };
__global__ __launch_bounds__(256, 3) void tmps_gemm(
    const unsigned short* __restrict__ Hb, const unsigned short* __restrict__ wz3,
    SPtrs sp)
{
  __shared__ union {
    unsigned short W[160 * WLD];   // 52,480 B (phase 1)
    float sq[128 * 65];            // 33,280 B (sym epilogue; stride 65)
  } sm;

  int z = blockIdx.x, tid = threadIdx.x;
  int g = z >> 8, bz = z & 255, b = bz >> 7;
  const unsigned short* Ab = Hb + c_xsel[g] * HROW + b * 128 * 160;  // X rows
  const unsigned short* Wb = wz3 + (long long)g * WZG + (long long)bz * NWZ;  // wz rows j
  int wave = tid >> 6, lane = tid & 63;
  int l15 = lane & 15, lq = lane >> 4;
  int X0 = wave * 32;                 // x-band per wave

  // ---------- stage whole W[160][160] (rows >=150 zero): 20 uint4 per row ----------
  for (int u = tid; u < 3200; u += 256) {
    int row = u / 20, q = u % 20;
    uint4 v; v.x = 0u; v.y = 0u; v.z = 0u; v.w = 0u;
    if (row < 150) v = *(const uint4*)&Wb[row * 160 + q * 8];
    *(uint4*)&sm.W[row * WLD + q * 8] = v;
  }
  __syncthreads();

  const unsigned short* Xr0 = Ab + (X0 + l15) * 160;
  const unsigned short* Xr1 = Ab + (X0 + 16 + l15) * 160;

  // ---------- phase 1 (swapped): accT[j-tile][x-tile] : D[j][x] = wz . X^T ----------
  facc4 accT[10][2];
  #pragma unroll
  for (int jt = 0; jt < 10; ++jt)
    #pragma unroll
    for (int xt = 0; xt < 2; ++xt) accT[jt][xt] = (facc4){0.f, 0.f, 0.f, 0.f};
  #pragma unroll
  for (int ks = 0; ks < 5; ++ks) {
    int ko = ks * 32 + (lq << 3);
    frag8 bx0 = *(const frag8*)&Xr0[ko];
    frag8 bx1 = *(const frag8*)&Xr1[ko];
    #pragma unroll
    for (int jt = 0; jt < 10; ++jt) {
      frag8 aw = *(const frag8*)&sm.W[(jt * 16 + l15) * WLD + ko];
      accT[jt][0] = __builtin_amdgcn_mfma_f32_16x16x32_bf16(aw, bx0, accT[jt][0], 0, 0, 0);
      accT[jt][1] = __builtin_amdgcn_mfma_f32_16x16x32_bf16(aw, bx1, accT[jt][1], 0, 0, 0);
    }
  }

  // ---------- repack accT -> phase-2 A-frags (f2u + __shfl, no asm) ----------
  // accT[jt][xt] lane(lq',l15'): holds tmp[x = X0+16xt+l15'][j = 16jt+4lq'+r].
  // pA[xt][kb] lane(lq,l15) needs tmp[x = X0+16xt+l15][j = 32kb+8lq+e], e=0..7,
  // packed as words (e0,e1)(e2,e3)(e4,e5)(e6,e7).
  // word w source: register pk(r0,r1 | r2,r3) of jt-tile 2kb+(lq>=2), from
  // source lane 32*(lq&1) + 16*(w>=2) + l15.
  frag8 pA[2][5];
  {
    int s0 = ((lq & 1) << 5) + l15;
    int s2 = s0 + 16;
    bool lo = lq < 2;
    #pragma unroll
    for (int kb = 0; kb < 5; ++kb)
      #pragma unroll
      for (int xt = 0; xt < 2; ++xt) {
        unsigned w0l = (unsigned)f2u(accT[2 * kb][xt][0]) |
                       ((unsigned)f2u(accT[2 * kb][xt][1]) << 16);
        unsigned w1l = (unsigned)f2u(accT[2 * kb][xt][2]) |
                       ((unsigned)f2u(accT[2 * kb][xt][3]) << 16);
        unsigned w0h = (unsigned)f2u(accT[2 * kb + 1][xt][0]) |
                       ((unsigned)f2u(accT[2 * kb + 1][xt][1]) << 16);
        unsigned w1h = (unsigned)f2u(accT[2 * kb + 1][xt][2]) |
                       ((unsigned)f2u(accT[2 * kb + 1][xt][3]) << 16);
        unsigned a0 = __shfl(w0l, s0), b0 = __shfl(w0h, s0);
        unsigned a1 = __shfl(w1l, s0), b1 = __shfl(w1h, s0);
        unsigned a2 = __shfl(w0l, s2), b2 = __shfl(w0h, s2);
        unsigned a3 = __shfl(w1l, s2), b3 = __shfl(w1h, s2);
        uint4v uv;
        uv.x = lo ? a0 : b0;
        uv.y = lo ? a1 : b1;
        uv.z = lo ? a2 : b2;
        uv.w = lo ? a3 : b3;
        pA[xt][kb] = __builtin_bit_cast(frag8, uv);
      }
  }

  // ---------- phase 2 (yt-halves): s[x][y] = sum_j tmp[x][j] * Y[y][j] ----------
  const unsigned short* Yb = Hb + c_ysel[g] * HROW + b * 128 * 160;
  float* C = sp.p[g] + (long long)bz * 16384;
  bool symg = (g >= 1 && g <= 3);
  for (int h = 0; h < 2; ++h) {
    facc4 acc2[2][4];
    #pragma unroll
    for (int xt = 0; xt < 2; ++xt)
      #pragma unroll
      for (int j = 0; j < 4; ++j) acc2[xt][j] = (facc4){0.f, 0.f, 0.f, 0.f};
    #pragma unroll
    for (int ks = 0; ks < 5; ++ks) {
      int ko = (ks << 5) + (lq << 3);
      #pragma unroll
      for (int j = 0; j < 4; ++j) {
        frag8 by = *(const frag8*)&Yb[((h * 4 + j) * 16 + l15) * 160 + ko];
        acc2[0][j] = __builtin_amdgcn_mfma_f32_16x16x32_bf16(pA[0][ks], by, acc2[0][j], 0, 0, 0);
        acc2[1][j] = __builtin_amdgcn_mfma_f32_16x16x32_bf16(pA[1][ks], by, acc2[1][j], 0, 0, 0);
      }
    }
    // direct writes: g0 full; g>=1 upper triangle (x<=y) only.
    // acc2 lane(q,c): x = X0 + xt*16 + 4q + r, y = (h*4+j)*16 + c.
    #pragma unroll
    for (int xt = 0; xt < 2; ++xt)
      #pragma unroll
      for (int r = 0; r < 4; ++r) {
        int x = X0 + xt * 16 + lq * 4 + r;
        #pragma unroll
        for (int j = 0; j < 4; ++j) {
          int y = (h * 4 + j) * 16 + l15;
          if (g == 0 || x <= y) C[x * 128 + y] = acc2[xt][j][r];
        }
      }
    if (symg) {
      // mirror s[min,max] into strict-lower via sq overlay (W dead).
      __syncthreads();   // h0: all Wsm reads done; h1: h0 mirror reads done
      if (h == 0) {
        // stage Q00 = s[x<64][y<64] (waves 0,1)
        if (wave < 2) {
          #pragma unroll
          for (int xt = 0; xt < 2; ++xt)
            #pragma unroll
            for (int r = 0; r < 4; ++r) {
              int x = X0 + xt * 16 + lq * 4 + r;
              #pragma unroll
              for (int j = 0; j < 4; ++j)
                sm.sq[x * 65 + j * 16 + l15] = acc2[xt][j][r];
            }
        }
        __syncthreads();
        // mirror x<64: out[x][y]=s[y][x], y<x; 16 rows/wave, y=lane
        #pragma unroll
        for (int it = 0; it < 16; ++it) {
          int x = wave * 16 + it;
          int y = lane;
          if (y < x) C[x * 128 + y] = sm.sq[y * 65 + x];
        }
      } else {
        // stage cols 64-127 from ALL waves: sq[x][y-64]
        #pragma unroll
        for (int xt = 0; xt < 2; ++xt)
          #pragma unroll
          for (int r = 0; r < 4; ++r) {
            int x = X0 + xt * 16 + lq * 4 + r;
            #pragma unroll
            for (int j = 0; j < 4; ++j)
              sm.sq[x * 65 + j * 16 + l15] = acc2[xt][j][r];
          }
        __syncthreads();
        // mirror x>=64: out[x][y]=s[y][x]=sq[y][x-64]; 16 rows/wave
        #pragma unroll
        for (int it = 0; it < 16; ++it) {
          int x = 64 + wave * 16 + it;
          int y1 = lane;            // y1 < 64 <= x always valid
          int y2 = 64 + lane;
          C[x * 128 + y1] = sm.sq[y1 * 65 + (x - 64)];
          if (y2 < x) C[x * 128 + y2] = sm.sq[y2 * 65 + (x - 64)];
        }
      }
    }
  }
}

// ---------- cop: out[b,x,y,z] = ss[g][b,z,min(x,y),max(x,y)]; grid (512,4,4) ----------
__global__ __launch_bounds__(256) void cop_kernel(
    const float* __restrict__ ss, float* __restrict__ out)
{
  int w0 = blockIdx.x << 5;
  int z0 = blockIdx.y << 5;
  int g  = blockIdx.z >> 1, b = blockIdx.z & 1;
  const float* sg = ss + (long long)g * OUTBLK;
  float* outp = out + (long long)(4 + g) * OUTBLK;
  __shared__ float tl[32][33];
  int tid = threadIdx.x;
  #pragma unroll
  for (int e = 0; e < 4; ++e) {
    int l = e * 256 + tid;
    int r = l >> 5, c = l & 31;
    int w = w0 + c;
    int xx = w >> 7, yy = w & 127;
    int sx = xx < yy ? xx : yy;
    int sy = xx < yy ? yy : xx;
    tl[r][c] = sg[(((b << 7) + z0 + r) << 14) + (sx << 7) + sy];
  }
  __syncthreads();
  #pragma unroll
  for (int e = 0; e < 4; ++e) {
    int l = e * 256 + tid;
    int rr = l >> 5, cc = l & 31;
    outp[(b << 21) + ((w0 + rr) << 7) + z0 + cc] = tl[cc][rr];
  }
}

extern "C" void kernel_launch(void* const* d_in, const int* in_sizes, int n_in,
                              void* d_out, int out_size, void* d_ws, size_t ws_size,
                              hipStream_t stream)
{
  const float* x   = (const float*)d_in[0];
  const float* Wsh = (const float*)d_in[1];
  const float* bsh = (const float*)d_in[2];
  const float* Wst = (const float*)d_in[3];
  const float* bst = (const float*)d_in[4];
  const float* Wp  = (const float*)d_in[5];
  const float* bp  = (const float*)d_in[6];
  TPtrs tp;
  tp.t[0] = (const float*)d_in[8];   // T_ph    (span_psh)
  tp.t[1] = (const float*)d_in[7];   // T_pt    (span_pst)
  tp.t[2] = (const float*)d_in[9];   // T_phsib
  tp.t[3] = (const float*)d_in[10];  // T_ptsib
  tp.t[4] = (const float*)d_in[11];  // T_phcop
  tp.t[5] = (const float*)d_in[12];  // T_ptcop
  float* out = (float*)d_out;
  char* wsb = (char*)d_ws;

  // ws layout (bytes): H 245,760 | TT3g 46,080,000 | wz3g 73,924,608
  // P (7.9MB) aliases wz3g (dead before wz writes); ss (33.6MB) aliases TT3g
  // (TT3 fully consumed by wz_gemm before tmps_gemm writes ss).
  unsigned short* Hb   = (unsigned short*)(wsb);
  unsigned short* TT3  = (unsigned short*)(wsb + 245760);
  unsigned short* wz3  = (unsigned short*)(wsb + 46325760);
  float* P  = (float*)wz3;
  float* ss = (float*)TT3;

  SPtrs sp;
  sp.p[0] = out + 0LL * OUTBLK;
  sp.p[1] = out + 1LL * OUTBLK;
  sp.p[2] = out + 2LL * OUTBLK;
  sp.p[3] = out + 3LL * OUTBLK;
  sp.p[4] = ss;
  sp.p[5] = ss + OUTBLK;

  mlp_partial<<<dim3(3, 8, 8),    256, 0, stream>>>(x, Wsh, Wst, Wp, P);
  mlp_reduce <<<dim3(480),        256, 0, stream>>>(P, bsh, bst, bp, Hb);
  tt_kernel  <<<dim3(160, 25, 6), 256, 0, stream>>>(tp, TT3);
  wz_gemm    <<<dim3(188, 2, 6),  256, 0, stream>>>(Hb, TT3, wz3);
  tmps_gemm  <<<dim3(1536),       256, 0, stream>>>(Hb, wz3, sp);
  cop_kernel <<<dim3(512, 4, 4),  256, 0, stream>>>(ss, out);
}